// Round 2
// baseline (583.860 us; speedup 1.0000x reference)
//
#include <hip/hip_runtime.h>
#include <hip/hip_bf16.h>
#include <math.h>

#define LOSS_WEIGHT 0.1f

typedef unsigned short u16;
typedef __bf16 bf16x8 __attribute__((ext_vector_type(8)));
typedef float f32x4 __attribute__((ext_vector_type(4)));

// ---- global -> LDS direct copy, 16B per lane (CK-style addrspace casts) ----
__device__ __forceinline__ void gload_lds16(const void* gsrc, void* ldst) {
    const __attribute__((address_space(1))) unsigned int* g =
        reinterpret_cast<const __attribute__((address_space(1))) unsigned int*>(
            reinterpret_cast<uintptr_t>(gsrc));
    __attribute__((address_space(3))) unsigned int* l =
        reinterpret_cast<__attribute__((address_space(3))) unsigned int*>(
            reinterpret_cast<uintptr_t>(ldst));
    __builtin_amdgcn_global_load_lds(g, l, 16, 0, 0);
}

__device__ __forceinline__ u16 f2b(float f) {
    __bf16 b = (__bf16)f;
    return __builtin_bit_cast(u16, b);
}

// ---- prep: f32 -> bf16 copies + row sum-of-squares for t and codebook ----
// one block (256 thr) per row; rows ordered [x(N) | t(N) | W(K) | C(K)]
__global__ __launch_bounds__(256) void prep_kernel(
    const float* __restrict__ x, const float* __restrict__ t,
    const float* __restrict__ W, const float* __restrict__ C,
    u16* __restrict__ xb, u16* __restrict__ tb,
    u16* __restrict__ wb, u16* __restrict__ cb,
    float* __restrict__ t_sq, float* __restrict__ c_sq,
    int N, int K, int H)
{
    int rid = blockIdx.x;
    const float* src; u16* dst; float* sq = nullptr; int row;
    if (rid < N)            { src = x; dst = xb; row = rid; }
    else if (rid < 2*N)     { src = t; dst = tb; row = rid - N; sq = t_sq; }
    else if (rid < 2*N + K) { src = W; dst = wb; row = rid - 2*N; }
    else                    { src = C; dst = cb; row = rid - 2*N - K; sq = c_sq; }

    const float* r = src + (size_t)row * H;
    u16* o = dst + (size_t)row * H;
    float acc = 0.f;
    for (int h = threadIdx.x * 4; h < H; h += blockDim.x * 4) {
        float4 v = *(const float4*)(r + h);
        acc += v.x*v.x + v.y*v.y + v.z*v.z + v.w*v.w;
        unsigned int lo = (unsigned int)f2b(v.x) | ((unsigned int)f2b(v.y) << 16);
        unsigned int hi = (unsigned int)f2b(v.z) | ((unsigned int)f2b(v.w) << 16);
        uint2 pk; pk.x = lo; pk.y = hi;
        *(uint2*)(o + h) = pk;
    }
    if (sq) {
        #pragma unroll
        for (int s = 1; s < 64; s <<= 1) acc += __shfl_xor(acc, s);
        __shared__ float wpart[4];
        if ((threadIdx.x & 63) == 0) wpart[threadIdx.x >> 6] = acc;
        __syncthreads();
        if (threadIdx.x == 0) sq[row] = wpart[0] + wpart[1] + wpart[2] + wpart[3];
    }
}

// ---- fused dual-GEMM + per-block online-softmax partials ----
// block: 256 thr (4 waves). tile: BM=64 tokens x BN=128 codebook entries, BH=64.
// wave w owns rows [w*16, w*16+16), all 128 cols.
// partial per (token, kblock): (rowmax m, sum exp(l-m), sum exp(l-m)*mse)
__global__ __launch_bounds__(256) void fused_gemm_kernel(
    const u16* __restrict__ xb, const u16* __restrict__ tb,
    const u16* __restrict__ wb, const u16* __restrict__ cb,
    const float* __restrict__ b_proj, const float* __restrict__ t_sq,
    const float* __restrict__ c_sq,
    float* __restrict__ pm, float* __restrict__ ps, float* __restrict__ pw,
    int H, float invD)
{
    __shared__ u16 xs[64 * 64];
    __shared__ u16 ts[64 * 64];
    __shared__ u16 ws[128 * 64];
    __shared__ u16 cs[128 * 64];

    const int tid  = threadIdx.x;
    const int lane = tid & 63;
    const int wv   = tid >> 6;
    const int kb   = blockIdx.x;           // codebook block (128 entries)
    const int mb   = blockIdx.y;           // token block (64 tokens)
    const int KB   = gridDim.x;
    const int m0   = mb * 64;
    const int k0   = kb * 128;

    f32x4 accL[8], accC[8];
    #pragma unroll
    for (int i = 0; i < 8; ++i) {
        accL[i] = (f32x4){0.f, 0.f, 0.f, 0.f};
        accC[i] = (f32x4){0.f, 0.f, 0.f, 0.f};
    }

    // swizzled ds_read base offsets (bytes). row stride = 128B; XOR bits 4-6
    // with (row&7) to kill the 16-way bank conflict. row&7 == lane&7 here.
    const int kx    = (lane & 7) << 4;
    const int koff0 = (((lane >> 4) << 4)) ^ kx;
    const int koff1 = (64 + ((lane >> 4) << 4)) ^ kx;
    const char* xs_b = (const char*)xs + (wv * 16 + (lane & 15)) * 128;
    const char* ts_b = (const char*)ts + (wv * 16 + (lane & 15)) * 128;
    const char* ws_b = (const char*)ws + (lane & 15) * 128;
    const char* cs_b = (const char*)cs + (lane & 15) * 128;

    const int e0 = tid * 8;  // element index this thread stages (8 bf16 = 16B)

    for (int h0 = 0; h0 < H; h0 += 64) {
        // stage: LDS dest is linear (base + lane*16B per wave); global source
        // is inverse-swizzled so swizzled reads find the right data.
        #pragma unroll
        for (int j = 0; j < 2; ++j) {
            int el  = j * 2048 + e0;
            int es  = el ^ (((el >> 6) & 7) << 3);
            int row = es >> 6, col = es & 63;
            gload_lds16(xb + (size_t)(m0 + row) * H + h0 + col, (u16*)xs + el);
            gload_lds16(tb + (size_t)(m0 + row) * H + h0 + col, (u16*)ts + el);
        }
        #pragma unroll
        for (int j = 0; j < 4; ++j) {
            int el  = j * 2048 + e0;
            int es  = el ^ (((el >> 6) & 7) << 3);
            int row = es >> 6, col = es & 63;
            gload_lds16(wb + (size_t)(k0 + row) * H + h0 + col, (u16*)ws + el);
            gload_lds16(cb + (size_t)(k0 + row) * H + h0 + col, (u16*)cs + el);
        }
        __syncthreads();

        #pragma unroll
        for (int kk = 0; kk < 2; ++kk) {
            const int ko = kk ? koff1 : koff0;
            bf16x8 ax = *(const bf16x8*)(xs_b + ko);
            bf16x8 at = *(const bf16x8*)(ts_b + ko);
            #pragma unroll
            for (int nf = 0; nf < 8; ++nf) {
                bf16x8 bw = *(const bf16x8*)(ws_b + nf * 2048 + ko);
                bf16x8 bc = *(const bf16x8*)(cs_b + nf * 2048 + ko);
                accL[nf] = __builtin_amdgcn_mfma_f32_16x16x32_bf16(ax, bw, accL[nf], 0, 0, 0);
                accC[nf] = __builtin_amdgcn_mfma_f32_16x16x32_bf16(at, bc, accC[nf], 0, 0, 0);
            }
        }
        __syncthreads();
    }

    // epilogue: C/D layout col = lane&15 (+16*nf), row = (lane>>4)*4 + j
    float bias[8], csq[8];
    #pragma unroll
    for (int nf = 0; nf < 8; ++nf) {
        int c = k0 + nf * 16 + (lane & 15);
        bias[nf] = b_proj[c];
        csq[nf]  = c_sq[c];
    }
    const int rbase = m0 + wv * 16 + ((lane >> 4) << 2);
    #pragma unroll
    for (int j = 0; j < 4; ++j) {
        const int row = rbase + j;
        const float tsq = t_sq[row];
        float lg[8], ms[8];
        float mx = -1e30f;
        #pragma unroll
        for (int nf = 0; nf < 8; ++nf) {
            lg[nf] = accL[nf][j] + bias[nf];
            ms[nf] = (tsq - 2.f * accC[nf][j] + csq[nf]) * invD;
            mx = fmaxf(mx, lg[nf]);
        }
        #pragma unroll
        for (int s = 1; s < 16; s <<= 1) mx = fmaxf(mx, __shfl_xor(mx, s));
        float esum = 0.f, wsum = 0.f;
        #pragma unroll
        for (int nf = 0; nf < 8; ++nf) {
            float e = __expf(lg[nf] - mx);
            esum += e;
            wsum += e * ms[nf];
        }
        #pragma unroll
        for (int s = 1; s < 16; s <<= 1) {
            esum += __shfl_xor(esum, s);
            wsum += __shfl_xor(wsum, s);
        }
        if ((lane & 15) == 0) {
            size_t idx = (size_t)row * KB + kb;
            pm[idx] = mx; ps[idx] = esum; pw[idx] = wsum;
        }
    }
}

// ---- finalize: merge per-kblock partials per token, mask, scale, atomic ----
__global__ __launch_bounds__(256) void finalize_kernel(
    const float* __restrict__ pm, const float* __restrict__ ps,
    const float* __restrict__ pw, const int* __restrict__ tti,
    float* __restrict__ out, int N, int KB)
{
    const int lane = threadIdx.x & 63;
    const int wv   = threadIdx.x >> 6;
    const int tok  = blockIdx.x * 4 + wv;
    float contrib = 0.f;
    if (tok < N) {
        const size_t base = (size_t)tok * KB;
        float m = -1e30f;
        for (int i = lane; i < KB; i += 64) m = fmaxf(m, pm[base + i]);
        #pragma unroll
        for (int s = 1; s < 64; s <<= 1) m = fmaxf(m, __shfl_xor(m, s));
        float esum = 0.f, wsum = 0.f;
        for (int i = lane; i < KB; i += 64) {
            float sc = __expf(pm[base + i] - m);
            esum += ps[base + i] * sc;
            wsum += pw[base + i] * sc;
        }
        #pragma unroll
        for (int s = 1; s < 64; s <<= 1) {
            esum += __shfl_xor(esum, s);
            wsum += __shfl_xor(wsum, s);
        }
        if (tti[tok] == 1) contrib = wsum / esum;
    }
    __shared__ float bsum[4];
    if (lane == 0) bsum[wv] = contrib;
    __syncthreads();
    if (threadIdx.x == 0) {
        float v = (bsum[0] + bsum[1] + bsum[2] + bsum[3]) * LOSS_WEIGHT;
        atomicAdd(out, v);
    }
}

extern "C" void kernel_launch(void* const* d_in, const int* in_sizes, int n_in,
                              void* d_out, int out_size, void* d_ws, size_t ws_size,
                              hipStream_t stream)
{
    const float* x   = (const float*)d_in[0];
    const int*   tti = (const int*)d_in[1];
    const float* t   = (const float*)d_in[2];
    const float* W   = (const float*)d_in[3];
    const float* b   = (const float*)d_in[4];
    const float* C   = (const float*)d_in[5];

    const int N  = in_sizes[1];           // B*S = 4096
    const int K  = in_sizes[4];           // 16384
    const int H  = in_sizes[0] / N;       // 1024
    const int KB = K / 128;

    char* p = (char*)d_ws;
    auto alloc = [&](size_t bytes) {
        char* r = p;
        p += (bytes + 255) & ~(size_t)255;
        return r;
    };
    u16*   xb   = (u16*)alloc((size_t)N * H * 2);
    u16*   tb   = (u16*)alloc((size_t)N * H * 2);
    u16*   wb   = (u16*)alloc((size_t)K * H * 2);
    u16*   cb   = (u16*)alloc((size_t)K * H * 2);
    float* t_sq = (float*)alloc((size_t)N * 4);
    float* c_sq = (float*)alloc((size_t)K * 4);
    float* pm   = (float*)alloc((size_t)N * KB * 4);
    float* ps   = (float*)alloc((size_t)N * KB * 4);
    float* pw   = (float*)alloc((size_t)N * KB * 4);

    hipMemsetAsync(d_out, 0, sizeof(float), stream);

    prep_kernel<<<2 * N + 2 * K, 256, 0, stream>>>(
        x, t, W, C, xb, tb, wb, cb, t_sq, c_sq, N, K, H);

    dim3 grid(K / 128, N / 64);
    fused_gemm_kernel<<<grid, 256, 0, stream>>>(
        xb, tb, wb, cb, b, t_sq, c_sq, pm, ps, pw, H, 1.f / (float)H);

    finalize_kernel<<<(N + 3) / 4, 256, 0, stream>>>(
        pm, ps, pw, tti, (float*)d_out, N, KB);
}

// Round 3
// 388.035 us; speedup vs baseline: 1.5047x; 1.5047x over previous
//
#include <hip/hip_runtime.h>
#include <hip/hip_bf16.h>
#include <math.h>

#define LOSS_WEIGHT 0.1f

typedef unsigned short u16;
typedef __bf16 bf16x8 __attribute__((ext_vector_type(8)));
typedef float f32x4 __attribute__((ext_vector_type(4)));

// ---- global -> LDS direct copy, 16B per lane ----
__device__ __forceinline__ void gload_lds16(const void* gsrc, void* ldst) {
    const __attribute__((address_space(1))) unsigned int* g =
        reinterpret_cast<const __attribute__((address_space(1))) unsigned int*>(
            reinterpret_cast<uintptr_t>(gsrc));
    __attribute__((address_space(3))) unsigned int* l =
        reinterpret_cast<__attribute__((address_space(3))) unsigned int*>(
            reinterpret_cast<uintptr_t>(ldst));
    __builtin_amdgcn_global_load_lds(g, l, 16, 0, 0);
}

__device__ __forceinline__ u16 f2b(float f) {
    __bf16 b = (__bf16)f;
    return __builtin_bit_cast(u16, b);
}

// ---- gather: compact indices of tokens with tti==1 ----
__global__ __launch_bounds__(256) void gather_kernel(
    const int* __restrict__ tti, int* __restrict__ idx_list,
    int* __restrict__ count, int N)
{
    int n = blockIdx.x * blockDim.x + threadIdx.x;
    if (n < N && tti[n] == 1) {
        int pos = atomicAdd(count, 1);
        idx_list[pos] = n;
    }
}

// ---- prep ----
// blocks [0, N): compacted token row rid — gather x,t rows via idx_list,
//   zero-pad rows in [count, count_padded64), skip beyond.
// blocks [N, N+K): W row. blocks [N+K, N+2K): C row.
__global__ __launch_bounds__(256) void prep_kernel(
    const float* __restrict__ x, const float* __restrict__ t,
    const float* __restrict__ W, const float* __restrict__ C,
    const int* __restrict__ idx_list, const int* __restrict__ count,
    u16* __restrict__ xb, u16* __restrict__ tb,
    u16* __restrict__ wb, u16* __restrict__ cb,
    float* __restrict__ t_sq, float* __restrict__ c_sq,
    int N, int K, int H)
{
    const int rid = blockIdx.x;

    if (rid < N) {
        const int cnt  = *count;
        const int cntp = (cnt + 63) & ~63;
        if (rid >= cntp) return;
        u16* ox = xb + (size_t)rid * H;
        u16* ot = tb + (size_t)rid * H;
        if (rid >= cnt) {
            for (int h = threadIdx.x * 4; h < H; h += blockDim.x * 4) {
                *(uint2*)(ox + h) = (uint2){0u, 0u};
                *(uint2*)(ot + h) = (uint2){0u, 0u};
            }
            if (threadIdx.x == 0) t_sq[rid] = 0.f;
            return;
        }
        const int src_row = idx_list[rid];
        const float* rx = x + (size_t)src_row * H;
        const float* rt = t + (size_t)src_row * H;
        float acc = 0.f;
        for (int h = threadIdx.x * 4; h < H; h += blockDim.x * 4) {
            float4 vx = *(const float4*)(rx + h);
            float4 vt = *(const float4*)(rt + h);
            acc += vt.x*vt.x + vt.y*vt.y + vt.z*vt.z + vt.w*vt.w;
            uint2 px, pt;
            px.x = (unsigned)f2b(vx.x) | ((unsigned)f2b(vx.y) << 16);
            px.y = (unsigned)f2b(vx.z) | ((unsigned)f2b(vx.w) << 16);
            pt.x = (unsigned)f2b(vt.x) | ((unsigned)f2b(vt.y) << 16);
            pt.y = (unsigned)f2b(vt.z) | ((unsigned)f2b(vt.w) << 16);
            *(uint2*)(ox + h) = px;
            *(uint2*)(ot + h) = pt;
        }
        #pragma unroll
        for (int s = 1; s < 64; s <<= 1) acc += __shfl_xor(acc, s);
        __shared__ float wpart[4];
        if ((threadIdx.x & 63) == 0) wpart[threadIdx.x >> 6] = acc;
        __syncthreads();
        if (threadIdx.x == 0) t_sq[rid] = wpart[0] + wpart[1] + wpart[2] + wpart[3];
        return;
    }

    // W / C rows
    const int wrid = rid - N;
    const float* src; u16* dst; float* sq = nullptr; int row;
    if (wrid < K) { src = W; dst = wb; row = wrid; }
    else          { src = C; dst = cb; row = wrid - K; sq = c_sq; }

    const float* r = src + (size_t)row * H;
    u16* o = dst + (size_t)row * H;
    float acc = 0.f;
    for (int h = threadIdx.x * 4; h < H; h += blockDim.x * 4) {
        float4 v = *(const float4*)(r + h);
        acc += v.x*v.x + v.y*v.y + v.z*v.z + v.w*v.w;
        uint2 pk;
        pk.x = (unsigned)f2b(v.x) | ((unsigned)f2b(v.y) << 16);
        pk.y = (unsigned)f2b(v.z) | ((unsigned)f2b(v.w) << 16);
        *(uint2*)(o + h) = pk;
    }
    if (sq) {
        #pragma unroll
        for (int s = 1; s < 64; s <<= 1) acc += __shfl_xor(acc, s);
        __shared__ float wpart2[4];
        if ((threadIdx.x & 63) == 0) wpart2[threadIdx.x >> 6] = acc;
        __syncthreads();
        if (threadIdx.x == 0) sq[row] = wpart2[0] + wpart2[1] + wpart2[2] + wpart2[3];
    }
}

// ---- fused dual-GEMM + per-block online-softmax partials ----
// block: 256 thr (4 waves). tile: BM=64 tokens x BN=128 codebook, BH=64.
__global__ __launch_bounds__(256) void fused_gemm_kernel(
    const u16* __restrict__ xb, const u16* __restrict__ tb,
    const u16* __restrict__ wb, const u16* __restrict__ cb,
    const float* __restrict__ b_proj, const float* __restrict__ t_sq,
    const float* __restrict__ c_sq, const int* __restrict__ count,
    float* __restrict__ pm, float* __restrict__ ps, float* __restrict__ pw,
    int H, float invD)
{
    const int mb = blockIdx.y;
    const int m0 = mb * 64;
    {
        const int cnt = *count;
        if (m0 >= ((cnt + 63) & ~63)) return;
    }

    __shared__ u16 xs[64 * 64];
    __shared__ u16 ts[64 * 64];
    __shared__ u16 ws[128 * 64];
    __shared__ u16 cs[128 * 64];

    const int tid  = threadIdx.x;
    const int lane = tid & 63;
    const int wv   = tid >> 6;
    const int kb   = blockIdx.x;
    const int KB   = gridDim.x;
    const int k0   = kb * 128;

    f32x4 accL[8], accC[8];
    #pragma unroll
    for (int i = 0; i < 8; ++i) {
        accL[i] = (f32x4){0.f, 0.f, 0.f, 0.f};
        accC[i] = (f32x4){0.f, 0.f, 0.f, 0.f};
    }

    // swizzled ds_read base offsets: row stride = 128B; XOR bits 4-6 with row&7
    const int kx    = (lane & 7) << 4;
    const int koff0 = (((lane >> 4) << 4)) ^ kx;
    const int koff1 = (64 + ((lane >> 4) << 4)) ^ kx;
    const char* xs_b = (const char*)xs + (wv * 16 + (lane & 15)) * 128;
    const char* ts_b = (const char*)ts + (wv * 16 + (lane & 15)) * 128;
    const char* ws_b = (const char*)ws + (lane & 15) * 128;
    const char* cs_b = (const char*)cs + (lane & 15) * 128;

    const int e0 = tid * 8;

    for (int h0 = 0; h0 < H; h0 += 64) {
        #pragma unroll
        for (int j = 0; j < 2; ++j) {
            int el  = j * 2048 + e0;
            int es  = el ^ (((el >> 6) & 7) << 3);
            int row = es >> 6, col = es & 63;
            gload_lds16(xb + (size_t)(m0 + row) * H + h0 + col, (u16*)xs + el);
            gload_lds16(tb + (size_t)(m0 + row) * H + h0 + col, (u16*)ts + el);
        }
        #pragma unroll
        for (int j = 0; j < 4; ++j) {
            int el  = j * 2048 + e0;
            int es  = el ^ (((el >> 6) & 7) << 3);
            int row = es >> 6, col = es & 63;
            gload_lds16(wb + (size_t)(k0 + row) * H + h0 + col, (u16*)ws + el);
            gload_lds16(cb + (size_t)(k0 + row) * H + h0 + col, (u16*)cs + el);
        }
        __syncthreads();

        #pragma unroll
        for (int kk = 0; kk < 2; ++kk) {
            const int ko = kk ? koff1 : koff0;
            bf16x8 ax = *(const bf16x8*)(xs_b + ko);
            bf16x8 at = *(const bf16x8*)(ts_b + ko);
            #pragma unroll
            for (int nf = 0; nf < 8; ++nf) {
                bf16x8 bw = *(const bf16x8*)(ws_b + nf * 2048 + ko);
                bf16x8 bc = *(const bf16x8*)(cs_b + nf * 2048 + ko);
                accL[nf] = __builtin_amdgcn_mfma_f32_16x16x32_bf16(ax, bw, accL[nf], 0, 0, 0);
                accC[nf] = __builtin_amdgcn_mfma_f32_16x16x32_bf16(at, bc, accC[nf], 0, 0, 0);
            }
        }
        __syncthreads();
    }

    float bias[8], csq[8];
    #pragma unroll
    for (int nf = 0; nf < 8; ++nf) {
        int c = k0 + nf * 16 + (lane & 15);
        bias[nf] = b_proj[c];
        csq[nf]  = c_sq[c];
    }
    const int rbase = m0 + wv * 16 + ((lane >> 4) << 2);
    #pragma unroll
    for (int j = 0; j < 4; ++j) {
        const int row = rbase + j;
        const float tsq = t_sq[row];
        float lg[8], ms[8];
        float mx = -1e30f;
        #pragma unroll
        for (int nf = 0; nf < 8; ++nf) {
            lg[nf] = accL[nf][j] + bias[nf];
            ms[nf] = (tsq - 2.f * accC[nf][j] + csq[nf]) * invD;
            mx = fmaxf(mx, lg[nf]);
        }
        #pragma unroll
        for (int s = 1; s < 16; s <<= 1) mx = fmaxf(mx, __shfl_xor(mx, s));
        float esum = 0.f, wsum = 0.f;
        #pragma unroll
        for (int nf = 0; nf < 8; ++nf) {
            float e = __expf(lg[nf] - mx);
            esum += e;
            wsum += e * ms[nf];
        }
        #pragma unroll
        for (int s = 1; s < 16; s <<= 1) {
            esum += __shfl_xor(esum, s);
            wsum += __shfl_xor(wsum, s);
        }
        if ((lane & 15) == 0) {
            size_t idx = (size_t)row * KB + kb;
            pm[idx] = mx; ps[idx] = esum; pw[idx] = wsum;
        }
    }
}

// ---- finalize: merge per-kblock partials per compacted token ----
__global__ __launch_bounds__(256) void finalize_kernel(
    const float* __restrict__ pm, const float* __restrict__ ps,
    const float* __restrict__ pw, const int* __restrict__ count,
    float* __restrict__ out, int KB)
{
    const int lane = threadIdx.x & 63;
    const int wv   = threadIdx.x >> 6;
    const int tok  = blockIdx.x * 4 + wv;
    const int cnt  = *count;
    float contrib = 0.f;
    if (tok < cnt) {
        const size_t base = (size_t)tok * KB;
        float m = -1e30f;
        for (int i = lane; i < KB; i += 64) m = fmaxf(m, pm[base + i]);
        #pragma unroll
        for (int s = 1; s < 64; s <<= 1) m = fmaxf(m, __shfl_xor(m, s));
        float esum = 0.f, wsum = 0.f;
        for (int i = lane; i < KB; i += 64) {
            float sc = __expf(pm[base + i] - m);
            esum += ps[base + i] * sc;
            wsum += pw[base + i] * sc;
        }
        #pragma unroll
        for (int s = 1; s < 64; s <<= 1) {
            esum += __shfl_xor(esum, s);
            wsum += __shfl_xor(wsum, s);
        }
        contrib = wsum / esum;
    }
    __shared__ float bsum[4];
    if (lane == 0) bsum[wv] = contrib;
    __syncthreads();
    if (threadIdx.x == 0) {
        float v = (bsum[0] + bsum[1] + bsum[2] + bsum[3]) * LOSS_WEIGHT;
        atomicAdd(out, v);
    }
}

extern "C" void kernel_launch(void* const* d_in, const int* in_sizes, int n_in,
                              void* d_out, int out_size, void* d_ws, size_t ws_size,
                              hipStream_t stream)
{
    const float* x   = (const float*)d_in[0];
    const int*   tti = (const int*)d_in[1];
    const float* t   = (const float*)d_in[2];
    const float* W   = (const float*)d_in[3];
    const float* b   = (const float*)d_in[4];
    const float* C   = (const float*)d_in[5];

    const int N  = in_sizes[1];           // B*S = 4096
    const int K  = in_sizes[4];           // 16384
    const int H  = in_sizes[0] / N;       // 1024
    const int KB = K / 128;

    char* p = (char*)d_ws;
    auto alloc = [&](size_t bytes) {
        char* r = p;
        p += (bytes + 255) & ~(size_t)255;
        return r;
    };
    u16*   xb   = (u16*)alloc((size_t)N * H * 2);
    u16*   tb   = (u16*)alloc((size_t)N * H * 2);
    u16*   wb   = (u16*)alloc((size_t)K * H * 2);
    u16*   cb   = (u16*)alloc((size_t)K * H * 2);
    float* t_sq = (float*)alloc((size_t)N * 4);
    float* c_sq = (float*)alloc((size_t)K * 4);
    float* pm   = (float*)alloc((size_t)N * KB * 4);
    float* ps   = (float*)alloc((size_t)N * KB * 4);
    float* pw   = (float*)alloc((size_t)N * KB * 4);
    int*   ilist= (int*)alloc((size_t)N * 4);
    int*   cnt  = (int*)alloc(4);

    hipMemsetAsync(d_out, 0, sizeof(float), stream);
    hipMemsetAsync(cnt, 0, sizeof(int), stream);

    gather_kernel<<<(N + 255) / 256, 256, 0, stream>>>(tti, ilist, cnt, N);

    prep_kernel<<<N + 2 * K, 256, 0, stream>>>(
        x, t, W, C, ilist, cnt, xb, tb, wb, cb, t_sq, c_sq, N, K, H);

    dim3 grid(K / 128, N / 64);
    fused_gemm_kernel<<<grid, 256, 0, stream>>>(
        xb, tb, wb, cb, b, t_sq, c_sq, cnt, pm, ps, pw, H, 1.f / (float)H);

    finalize_kernel<<<(N + 3) / 4, 256, 0, stream>>>(
        pm, ps, pw, cnt, (float*)d_out, KB);
}

// Round 5
// 385.929 us; speedup vs baseline: 1.5129x; 1.0055x over previous
//
#include <hip/hip_runtime.h>
#include <hip/hip_bf16.h>
#include <math.h>

#define LOSS_WEIGHT 0.1f

typedef unsigned short u16;
typedef __bf16 bf16x8 __attribute__((ext_vector_type(8)));
typedef float f32x4 __attribute__((ext_vector_type(4)));

// ---- global -> LDS direct copy, 16B per lane ----
__device__ __forceinline__ void gload_lds16(const void* gsrc, void* ldst) {
    const __attribute__((address_space(1))) unsigned int* g =
        reinterpret_cast<const __attribute__((address_space(1))) unsigned int*>(
            reinterpret_cast<uintptr_t>(gsrc));
    __attribute__((address_space(3))) unsigned int* l =
        reinterpret_cast<__attribute__((address_space(3))) unsigned int*>(
            reinterpret_cast<uintptr_t>(ldst));
    __builtin_amdgcn_global_load_lds(g, l, 16, 0, 0);
}

__device__ __forceinline__ u16 f2b(float f) {
    __bf16 b = (__bf16)f;
    return __builtin_bit_cast(u16, b);
}
__device__ __forceinline__ unsigned pack2(float a, float b) {
    return (unsigned)f2b(a) | ((unsigned)f2b(b) << 16);
}

// ---- gather: compact indices of tokens with tti==1 ----
__global__ __launch_bounds__(256) void gather_kernel(
    const int* __restrict__ tti, int* __restrict__ idx_list,
    int* __restrict__ count, int N)
{
    int n = blockIdx.x * blockDim.x + threadIdx.x;
    if (n < N && tti[n] == 1) {
        int pos = atomicAdd(count, 1);
        idx_list[pos] = n;
    }
}

// ---- prep: one WAVE per row, 4 rows per block ----
// blocks [0, N/4): token rows (gather x,t via idx_list, zero-pad to 128-align)
// blocks [N/4, N/4+K/4): W rows. next K/4: C rows.
__global__ __launch_bounds__(256) void prep_kernel(
    const float* __restrict__ x, const float* __restrict__ t,
    const float* __restrict__ W, const float* __restrict__ C,
    const int* __restrict__ idx_list, const int* __restrict__ count,
    u16* __restrict__ xb, u16* __restrict__ tb,
    u16* __restrict__ wb, u16* __restrict__ cb,
    float* __restrict__ t_sq, float* __restrict__ c_sq,
    int N, int K, int H)
{
    const int lane = threadIdx.x & 63;
    const int wv   = threadIdx.x >> 6;
    const int NT   = N >> 2, KQ = K >> 2;
    const int bid  = blockIdx.x;

    if (bid < NT) {
        const int rid  = bid * 4 + wv;
        const int cnt  = *count;
        const int cntp = (cnt + 127) & ~127;
        if (rid >= cntp) return;
        u16* ox = xb + (size_t)rid * H;
        u16* ot = tb + (size_t)rid * H;
        if (rid >= cnt) {
            for (int p = lane * 8; p < H; p += 512) {
                *(uint4*)(ox + p) = (uint4){0u, 0u, 0u, 0u};
                *(uint4*)(ot + p) = (uint4){0u, 0u, 0u, 0u};
            }
            if (lane == 0) t_sq[rid] = 0.f;
            return;
        }
        const int src_row = idx_list[rid];
        const float* rx = x + (size_t)src_row * H;
        const float* rt = t + (size_t)src_row * H;
        float acc = 0.f;
        for (int p = lane * 8; p < H; p += 512) {
            float4 xa = *(const float4*)(rx + p);
            float4 xbv = *(const float4*)(rx + p + 4);
            float4 ta = *(const float4*)(rt + p);
            float4 tbv = *(const float4*)(rt + p + 4);
            acc += ta.x*ta.x + ta.y*ta.y + ta.z*ta.z + ta.w*ta.w
                 + tbv.x*tbv.x + tbv.y*tbv.y + tbv.z*tbv.z + tbv.w*tbv.w;
            uint4 px = {pack2(xa.x, xa.y), pack2(xa.z, xa.w),
                        pack2(xbv.x, xbv.y), pack2(xbv.z, xbv.w)};
            uint4 pt = {pack2(ta.x, ta.y), pack2(ta.z, ta.w),
                        pack2(tbv.x, tbv.y), pack2(tbv.z, tbv.w)};
            *(uint4*)(ox + p) = px;
            *(uint4*)(ot + p) = pt;
        }
        #pragma unroll
        for (int s = 1; s < 64; s <<= 1) acc += __shfl_xor(acc, s);
        if (lane == 0) t_sq[rid] = acc;
        return;
    }

    // W / C rows
    const int wbid = bid - NT;
    const float* src; u16* dst; float* sq = nullptr; int row;
    if (wbid < KQ) { src = W; dst = wb; row = wbid * 4 + wv; }
    else           { src = C; dst = cb; row = (wbid - KQ) * 4 + wv; sq = c_sq; }

    const float* r = src + (size_t)row * H;
    u16* o = dst + (size_t)row * H;
    float acc = 0.f;
    for (int p = lane * 8; p < H; p += 512) {
        float4 a = *(const float4*)(r + p);
        float4 b = *(const float4*)(r + p + 4);
        acc += a.x*a.x + a.y*a.y + a.z*a.z + a.w*a.w
             + b.x*b.x + b.y*b.y + b.z*b.z + b.w*b.w;
        uint4 pk = {pack2(a.x, a.y), pack2(a.z, a.w),
                    pack2(b.x, b.y), pack2(b.z, b.w)};
        *(uint4*)(o + p) = pk;
    }
    if (sq) {
        #pragma unroll
        for (int s = 1; s < 64; s <<= 1) acc += __shfl_xor(acc, s);
        if (lane == 0) sq[row] = acc;
    }
}

// ---- fused dual-GEMM + per-half-tile online-softmax partials ----
// block: 256 thr (4 waves, 2x2). tile: BM=128 tokens x BN=128 codebook, BK=64.
// wave (wr,wc) owns a 64x64 sub-tile of each output: 4x4 fragments of 16x16.
__global__ __launch_bounds__(256, 2) void fused_gemm_kernel(
    const u16* __restrict__ xb, const u16* __restrict__ tb,
    const u16* __restrict__ wb, const u16* __restrict__ cb,
    const float* __restrict__ b_proj, const float* __restrict__ t_sq,
    const float* __restrict__ c_sq, const int* __restrict__ count,
    float* __restrict__ pm, float* __restrict__ ps, float* __restrict__ pw,
    int H, float invD)
{
    const int mb = blockIdx.y;
    const int m0 = mb * 128;
    {
        const int cnt = *count;
        if (m0 >= ((cnt + 127) & ~127)) return;
    }

    __shared__ u16 xs[128 * 64];
    __shared__ u16 ts[128 * 64];
    __shared__ u16 ws[128 * 64];
    __shared__ u16 cs[128 * 64];

    const int tid  = threadIdx.x;
    const int lane = tid & 63;
    const int wv   = tid >> 6;
    const int wr   = wv >> 1;          // row half (0/1)
    const int wc   = wv & 1;           // col half (0/1)
    const int kb   = blockIdx.x;
    const int KB2  = gridDim.x * 2;
    const int k0   = kb * 128;

    f32x4 accL[16], accC[16];
    #pragma unroll
    for (int i = 0; i < 16; ++i) {
        accL[i] = (f32x4){0.f, 0.f, 0.f, 0.f};
        accC[i] = (f32x4){0.f, 0.f, 0.f, 0.f};
    }

    // swizzled ds_read offsets: row stride 128B; XOR byte bits 4-6 with row&7
    const int kx    = (lane & 7) << 4;
    const int koff0 = (((lane >> 4) << 4)) ^ kx;
    const int koff1 = (64 + ((lane >> 4) << 4)) ^ kx;
    const char* xs_b = (const char*)xs + (wr * 64 + (lane & 15)) * 128;
    const char* ts_b = (const char*)ts + (wr * 64 + (lane & 15)) * 128;
    const char* ws_b = (const char*)ws + (wc * 64 + (lane & 15)) * 128;
    const char* cs_b = (const char*)cs + (wc * 64 + (lane & 15)) * 128;

    const int e0 = tid * 8;

    for (int h0 = 0; h0 < H; h0 += 64) {
        #pragma unroll
        for (int j = 0; j < 4; ++j) {
            int el  = j * 2048 + e0;
            int es  = el ^ (((el >> 6) & 7) << 3);
            int row = es >> 6, col = es & 63;
            gload_lds16(xb + (size_t)(m0 + row) * H + h0 + col, (u16*)xs + el);
            gload_lds16(tb + (size_t)(m0 + row) * H + h0 + col, (u16*)ts + el);
            gload_lds16(wb + (size_t)(k0 + row) * H + h0 + col, (u16*)ws + el);
            gload_lds16(cb + (size_t)(k0 + row) * H + h0 + col, (u16*)cs + el);
        }
        __syncthreads();

        #pragma unroll
        for (int kk = 0; kk < 2; ++kk) {
            const int ko = kk ? koff1 : koff0;
            bf16x8 ax[4], at[4], bw[4], bc[4];
            #pragma unroll
            for (int i = 0; i < 4; ++i) {
                ax[i] = *(const bf16x8*)(xs_b + i * 2048 + ko);
                at[i] = *(const bf16x8*)(ts_b + i * 2048 + ko);
                bw[i] = *(const bf16x8*)(ws_b + i * 2048 + ko);
                bc[i] = *(const bf16x8*)(cs_b + i * 2048 + ko);
            }
            #pragma unroll
            for (int mi = 0; mi < 4; ++mi) {
                #pragma unroll
                for (int ni = 0; ni < 4; ++ni) {
                    accL[mi * 4 + ni] = __builtin_amdgcn_mfma_f32_16x16x32_bf16(
                        ax[mi], bw[ni], accL[mi * 4 + ni], 0, 0, 0);
                    accC[mi * 4 + ni] = __builtin_amdgcn_mfma_f32_16x16x32_bf16(
                        at[mi], bc[ni], accC[mi * 4 + ni], 0, 0, 0);
                }
            }
        }
        __syncthreads();
    }

    // epilogue: C/D layout col = lane&15 (+16*ni), row = (lane>>4)*4 + j (+16*mi)
    float bias[4], csq[4];
    #pragma unroll
    for (int ni = 0; ni < 4; ++ni) {
        int c = k0 + wc * 64 + ni * 16 + (lane & 15);
        bias[ni] = b_proj[c];
        csq[ni]  = c_sq[c];
    }
    const int rbase = m0 + wr * 64 + ((lane >> 4) << 2);
    #pragma unroll
    for (int mi = 0; mi < 4; ++mi) {
        #pragma unroll
        for (int j = 0; j < 4; ++j) {
            const int row = rbase + mi * 16 + j;
            const float tsq = t_sq[row];
            float lg[4], ms[4];
            float mx = -1e30f;
            #pragma unroll
            for (int ni = 0; ni < 4; ++ni) {
                lg[ni] = accL[mi * 4 + ni][j] + bias[ni];
                ms[ni] = (tsq - 2.f * accC[mi * 4 + ni][j] + csq[ni]) * invD;
                mx = fmaxf(mx, lg[ni]);
            }
            #pragma unroll
            for (int s = 1; s < 16; s <<= 1) mx = fmaxf(mx, __shfl_xor(mx, s));
            float esum = 0.f, wsum = 0.f;
            #pragma unroll
            for (int ni = 0; ni < 4; ++ni) {
                float e = __expf(lg[ni] - mx);
                esum += e;
                wsum += e * ms[ni];
            }
            #pragma unroll
            for (int s = 1; s < 16; s <<= 1) {
                esum += __shfl_xor(esum, s);
                wsum += __shfl_xor(wsum, s);
            }
            if ((lane & 15) == 0) {
                size_t idx = (size_t)row * KB2 + kb * 2 + wc;
                pm[idx] = mx; ps[idx] = esum; pw[idx] = wsum;
            }
        }
    }
}

// ---- finalize: merge per-half-tile partials per compacted token ----
__global__ __launch_bounds__(256) void finalize_kernel(
    const float* __restrict__ pm, const float* __restrict__ ps,
    const float* __restrict__ pw, const int* __restrict__ count,
    float* __restrict__ out, int KB2)
{
    const int lane = threadIdx.x & 63;
    const int wv   = threadIdx.x >> 6;
    const int tok  = blockIdx.x * 4 + wv;
    const int cnt  = *count;
    float contrib = 0.f;
    if (tok < cnt) {
        const size_t base = (size_t)tok * KB2;
        float m = -1e30f;
        for (int i = lane; i < KB2; i += 64) m = fmaxf(m, pm[base + i]);
        #pragma unroll
        for (int s = 1; s < 64; s <<= 1) m = fmaxf(m, __shfl_xor(m, s));
        float esum = 0.f, wsum = 0.f;
        for (int i = lane; i < KB2; i += 64) {
            float sc = __expf(pm[base + i] - m);
            esum += ps[base + i] * sc;
            wsum += pw[base + i] * sc;
        }
        #pragma unroll
        for (int s = 1; s < 64; s <<= 1) {
            esum += __shfl_xor(esum, s);
            wsum += __shfl_xor(wsum, s);
        }
        contrib = wsum / esum;
    }
    __shared__ float bsum[4];
    if (lane == 0) bsum[wv] = contrib;
    __syncthreads();
    if (threadIdx.x == 0) {
        float v = (bsum[0] + bsum[1] + bsum[2] + bsum[3]) * LOSS_WEIGHT;
        atomicAdd(out, v);
    }
}

extern "C" void kernel_launch(void* const* d_in, const int* in_sizes, int n_in,
                              void* d_out, int out_size, void* d_ws, size_t ws_size,
                              hipStream_t stream)
{
    const float* x   = (const float*)d_in[0];
    const int*   tti = (const int*)d_in[1];
    const float* t   = (const float*)d_in[2];
    const float* W   = (const float*)d_in[3];
    const float* b   = (const float*)d_in[4];
    const float* C   = (const float*)d_in[5];

    const int N   = in_sizes[1];           // B*S = 4096
    const int K   = in_sizes[4];           // 16384
    const int H   = in_sizes[0] / N;       // 1024
    const int KB2 = K / 64;                // partial slots per token

    char* p = (char*)d_ws;
    auto alloc = [&](size_t bytes) {
        char* r = p;
        p += (bytes + 255) & ~(size_t)255;
        return r;
    };
    u16*   xb   = (u16*)alloc((size_t)N * H * 2);
    u16*   tb   = (u16*)alloc((size_t)N * H * 2);
    u16*   wb   = (u16*)alloc((size_t)K * H * 2);
    u16*   cb   = (u16*)alloc((size_t)K * H * 2);
    float* t_sq = (float*)alloc((size_t)N * 4);
    float* c_sq = (float*)alloc((size_t)K * 4);
    float* pm   = (float*)alloc((size_t)N * KB2 * 4);
    float* ps   = (float*)alloc((size_t)N * KB2 * 4);
    float* pw   = (float*)alloc((size_t)N * KB2 * 4);
    int*   ilist= (int*)alloc((size_t)N * 4);
    int*   cnt  = (int*)alloc(4);

    hipMemsetAsync(d_out, 0, sizeof(float), stream);
    hipMemsetAsync(cnt, 0, sizeof(int), stream);

    gather_kernel<<<(N + 255) / 256, 256, 0, stream>>>(tti, ilist, cnt, N);

    prep_kernel<<<N / 4 + K / 2, 256, 0, stream>>>(
        x, t, W, C, ilist, cnt, xb, tb, wb, cb, t_sq, c_sq, N, K, H);

    dim3 grid(K / 128, N / 128);
    fused_gemm_kernel<<<grid, 256, 0, stream>>>(
        xb, tb, wb, cb, b, t_sq, c_sq, cnt, pm, ps, pw, H, 1.f / (float)H);

    finalize_kernel<<<(N + 3) / 4, 256, 0, stream>>>(
        pm, ps, pw, cnt, (float*)d_out, KB2);
}